// Round 3
// baseline (1780.892 us; speedup 1.0000x reference)
//
#include <hip/hip_runtime.h>

#define D 512
#define T 50000
#define T4 12500          // T/4 float4 columns
#define K 16

#define S 16              // row slices
#define RS (D / S)        // 32 rows per slice
#define CG 49             // column groups = ceil(T4/256)

#define LAMBDA1 0.3366f
#define LR      0.1f
#define SHRINK_C (LR * LAMBDA1)
#define BETA1   0.9f
#define BETA2   0.999f
#define ADAM_EPS 1e-8f

__device__ __forceinline__ float sgn(float x) {
    return (x > 0.f) ? 1.f : ((x < 0.f) ? -1.f : 0.f);
}

// Zero all state. d_ws is poisoned 0xAA before every call.
__global__ void init_kernel(const float* __restrict__ Pin, float* __restrict__ P,
                            float* __restrict__ m, float* __restrict__ v,
                            float* __restrict__ B, unsigned long long* slot,
                            int* colDone, int* doneCnt) {
    int idx = blockIdx.x * blockDim.x + threadIdx.x;
    if (idx < D * K) {
        float p = Pin[idx];
        P[idx] = p;
        m[idx] = 0.f;
        v[idx] = 0.f;
        B[idx] = p;   // iteration 1 uses the raw parameter
    }
    if (idx < CG) colDone[idx] = 0;
    if (idx == CG) *doneCnt = 0;
    if (idx == CG + 1) *slot = 0ull;
}

// One fused iteration:
//   phase 1: block (bx, s) computes partial colsums for 1024 cols x 32 rows
//   phase 2: last slice-block per column group sums the 16 partials, block
//            argmax, atomicMax into packed (sum_bits<<32|j) slot
//   phase 3: last reducer block does signs, B col-L1 argmax, Adam, shrink,
//            and resets the counters/slot for the next iteration.
__global__ __launch_bounds__(256) void iter_kernel(
        const float* __restrict__ E, const float* __restrict__ A,
        float* __restrict__ B, float* __restrict__ P,
        float* __restrict__ m, float* __restrict__ v,
        unsigned long long* slot, int* colDone, int* doneCnt,
        float4* __restrict__ partial4,
        float bias1, float bias2, int shrinkGrad) {
    const int tid = threadIdx.x;
    const int bx  = blockIdx.x;          // column group 0..CG-1
    const int s   = blockIdx.y;          // row slice 0..S-1
    const int j4  = bx * 256 + tid;      // float4 column index
    const bool active = (j4 < T4);

    const float4* E4 = (const float4*)E;
    const float4* A4 = (const float4*)A;

    // ---- phase 1: partial column abs-sums over rows [s*RS, s*RS+RS) ----
    if (active) {
        float4 a[K];
#pragma unroll
        for (int k = 0; k < K; ++k) a[k] = A4[k * T4 + j4];

        float4 acc = make_float4(0.f, 0.f, 0.f, 0.f);
        const int r0 = s * RS;
#pragma unroll 4
        for (int ii = 0; ii < RS; ++ii) {
            const int i = r0 + ii;
            const float* Br = B + i * K;         // wave-uniform -> s_load
            float4 e = E4[i * T4 + j4];
#pragma unroll
            for (int k = 0; k < K; ++k) {
                float bk = Br[k];
                e.x -= bk * a[k].x;
                e.y -= bk * a[k].y;
                e.z -= bk * a[k].z;
                e.w -= bk * a[k].w;
            }
            acc.x += fabsf(e.x);
            acc.y += fabsf(e.y);
            acc.z += fabsf(e.z);
            acc.w += fabsf(e.w);
        }
        partial4[s * T4 + j4] = acc;
    }

    // make this block's partial stores device-visible, then signal
    __threadfence();
    __syncthreads();
    __shared__ int flag_s;
    if (tid == 0)
        flag_s = (atomicAdd(&colDone[bx], 1) == S - 1) ? 1 : 0;
    __syncthreads();
    if (!flag_s) return;

    // ---- phase 2: this block is the last slice for column group bx ----
    if (tid == 0) __threadfence();   // acquire: invalidate L1 before partial reads
    __syncthreads();

    unsigned long long key = 0ull;
    if (active) {
        float4 sum = make_float4(0.f, 0.f, 0.f, 0.f);
#pragma unroll
        for (int ss = 0; ss < S; ++ss) {
            float4 p = partial4[ss * T4 + j4];
            sum.x += p.x; sum.y += p.y; sum.z += p.z; sum.w += p.w;
        }
        float best = sum.x; int jb = 4 * j4;
        if (sum.y > best) { best = sum.y; jb = 4 * j4 + 1; }
        if (sum.z > best) { best = sum.z; jb = 4 * j4 + 2; }
        if (sum.w > best) { best = sum.w; jb = 4 * j4 + 3; }
        // best >= 0 -> float bits order-preserving as unsigned
        key = (((unsigned long long)__float_as_uint(best)) << 32) | (unsigned int)jb;
    }
#pragma unroll
    for (int off = 32; off > 0; off >>= 1) {
        unsigned long long o = __shfl_down(key, off, 64);
        if (o > key) key = o;
    }
    __shared__ unsigned long long wmax[4];
    int lane = tid & 63, wid = tid >> 6;
    if (lane == 0) wmax[wid] = key;
    __syncthreads();
    if (tid == 0) {
        unsigned long long bk = wmax[0];
        for (int w = 1; w < 4; ++w)
            if (wmax[w] > bk) bk = wmax[w];
        atomicMax(slot, bk);
    }

    __threadfence();
    __syncthreads();
    if (tid == 0)
        flag_s = (atomicAdd(doneCnt, 1) == CG - 1) ? 1 : 0;
    __syncthreads();
    if (!flag_s) return;

    // ---- phase 3: last reducer block does the parameter update ----
    __shared__ int js_s, ks_s;
    __shared__ float colB[K];
    if (tid == 0) {
        // atomic read -> coherent view of all reducers' atomicMax results
        unsigned long long v0 = atomicMax(slot, 0ull);
        js_s = (int)(v0 & 0xffffffffull);
    }
    if (tid < K) colB[tid] = 0.f;
    __syncthreads();
    const int js = js_s;

    const int i0 = tid;          // row pair: tid and tid+256
    const int i1 = tid + 256;

    float b0[K], b1v[K];
#pragma unroll
    for (int k = 0; k < K; ++k) { b0[k] = B[i0 * K + k]; b1v[k] = B[i1 * K + k]; }

    float r0v = E[i0 * T + js];
    float r1v = E[i1 * T + js];
#pragma unroll
    for (int k = 0; k < K; ++k) {
        float ak = A[k * T + js];
        r0v -= b0[k] * ak;
        r1v -= b1v[k] * ak;
    }
    const float s0 = sgn(r0v), s1 = sgn(r1v);

    // B column abs-sums: wave reduce then one LDS atomic per wave per k
#pragma unroll
    for (int k = 0; k < K; ++k) {
        float x = fabsf(b0[k]) + fabsf(b1v[k]);
#pragma unroll
        for (int off = 32; off > 0; off >>= 1) x += __shfl_down(x, off, 64);
        if ((tid & 63) == 0) atomicAdd(&colB[k], x);
    }
    __syncthreads();
    if (tid == 0) {
        int kb = 0;
        float best = colB[0];
        for (int k = 1; k < K; ++k)
            if (colB[k] > best) { best = colB[k]; kb = k; }  // first-max tie-break
        ks_s = kb;
    }
    __syncthreads();
    const int ks = ks_s;

#pragma unroll
    for (int k = 0; k < K; ++k) {
        float ak = A[k * T + js];
#pragma unroll
        for (int h = 0; h < 2; ++h) {
            const int i = h ? i1 : i0;
            const float sg = h ? s1 : s0;
            const float bk = h ? b1v[k] : b0[k];
            float g = -sg * ak;
            if (k == ks) g += LAMBDA1 * sgn(bk);
            float p = P[i * K + k];
            if (shrinkGrad) g *= sgn(p) * sgn(p - SHRINK_C);  // d shrink/dp a.e.
            float mm = BETA1 * m[i * K + k] + (1.f - BETA1) * g;
            float vv = BETA2 * v[i * K + k] + (1.f - BETA2) * g * g;
            m[i * K + k] = mm;
            v[i * K + k] = vv;
            p -= LR * (mm / bias1) / (sqrtf(vv / bias2) + ADAM_EPS);
            P[i * K + k] = p;
            B[i * K + k] = sgn(p) * fmaxf(0.f, fabsf(p - SHRINK_C)); // next B
        }
    }

    // reset counters/slot for the next iteration (kernel boundary publishes)
    if (tid < CG) colDone[tid] = 0;
    if (tid == CG) *doneCnt = 0;
    if (tid == CG + 1) *slot = 0ull;
}

// out = [shrink(P_final) (8192), A (800000)]. B already holds shrink(P_final).
__global__ void output_kernel(const float* __restrict__ B, const float* __restrict__ A,
                              float4* __restrict__ out) {
    int idx = blockIdx.x * blockDim.x + threadIdx.x;   // float4 units
    const int nB4 = (D * K) / 4;                       // 2048
    const int nTot4 = (D * K + K * T) / 4;             // 202048
    if (idx < nB4) {
        out[idx] = ((const float4*)B)[idx];
    } else if (idx < nTot4) {
        out[idx] = ((const float4*)A)[idx - nB4];
    }
}

extern "C" void kernel_launch(void* const* d_in, const int* in_sizes, int n_in,
                              void* d_out, int out_size, void* d_ws, size_t ws_size,
                              hipStream_t stream) {
    const float* E   = (const float*)d_in[0];   // (D, T)
    const float* Bin = (const float*)d_in[1];   // (D, K)
    const float* A   = (const float*)d_in[2];   // (K, T)

    float* P = (float*)d_ws;
    float* m = P + D * K;
    float* v = m + D * K;
    float* B = v + D * K;
    unsigned long long* slot = (unsigned long long*)(B + D * K);
    int* colDone = (int*)(slot + 2);
    int* doneCnt = colDone + CG;
    // align partial to 16B
    float4* partial4 = (float4*)((char*)d_ws + ((4u * D * K + 64u + CG + 8u) * 4u + 127u & ~127u));

    init_kernel<<<(D * K + 255) / 256, 256, 0, stream>>>(Bin, P, m, v, B, slot,
                                                         colDone, doneCnt);

    for (int it = 1; it <= 10; ++it) {
        float b1 = 1.f - powf(BETA1, (float)it);
        float b2 = 1.f - powf(BETA2, (float)it);
        iter_kernel<<<dim3(CG, S), 256, 0, stream>>>(E, A, B, P, m, v, slot,
                                                     colDone, doneCnt, partial4,
                                                     b1, b2, (it >= 2) ? 1 : 0);
    }

    const int nTot4 = (D * K + K * T) / 4;
    output_kernel<<<(nTot4 + 255) / 256, 256, 0, stream>>>(B, A, (float4*)d_out);
}

// Round 4
// 789.704 us; speedup vs baseline: 2.2551x; 2.2551x over previous
//
#include <hip/hip_runtime.h>

#define D 512
#define T 50000
#define T4 12500          // T/4 float4 columns
#define K 16

#define S 32              // row slices
#define RS (D / S)        // 16 rows per slice
#define CB 49             // column blocks = ceil(T4/256)

#define LAMBDA1 0.3366f
#define LR      0.1f
#define SHRINK_C (LR * LAMBDA1)
#define BETA1   0.9f
#define BETA2   0.999f
#define ADAM_EPS 1e-8f

__device__ __forceinline__ float sgn(float x) {
    return (x > 0.f) ? 1.f : ((x < 0.f) ? -1.f : 0.f);
}

// Initialize P, m, v, B (=P for iter 1) and the argmax slot. d_ws is poisoned
// 0xAA before every call, so everything must be re-initialized here.
__global__ void init_kernel(const float* __restrict__ Pin, float* __restrict__ P,
                            float* __restrict__ m, float* __restrict__ v,
                            float* __restrict__ B, unsigned long long* slot) {
    int idx = blockIdx.x * blockDim.x + threadIdx.x;
    if (idx < D * K) {
        float p = Pin[idx];
        P[idx] = p;
        m[idx] = 0.f;
        v[idx] = 0.f;
        B[idx] = p;   // iteration 1 uses the raw parameter
    }
    if (idx == 0) *slot = 0ull;
}

// Partial column abs-sums, float4 columns: block (bx, s) covers 1024 scalar
// columns x 16 rows. Thread j4 accumulates 4 columns' partial sums and writes
// partial4[s*T4 + j4]. Deterministic (no fp atomics). No fences — the kernel
// boundary publishes the stores (R2 showed device-scope fences cost 3x).
__global__ __launch_bounds__(256) void partial_colsum_kernel(
        const float* __restrict__ E, const float* __restrict__ A,
        const float* __restrict__ B, float4* __restrict__ partial4) {
    const int j4 = blockIdx.x * blockDim.x + threadIdx.x;
    const int s  = blockIdx.y;
    if (j4 >= T4) return;

    const float4* E4 = (const float4*)E;
    const float4* A4 = (const float4*)A;

    float4 a[K];
#pragma unroll
    for (int k = 0; k < K; ++k) a[k] = A4[k * T4 + j4];

    float4 acc = make_float4(0.f, 0.f, 0.f, 0.f);
    const int r0 = s * RS;
#pragma unroll 4
    for (int ii = 0; ii < RS; ++ii) {
        const int i = r0 + ii;
        const float* Br = B + i * K;     // wave-uniform address -> s_load
        float4 e = E4[i * T4 + j4];
#pragma unroll
        for (int k = 0; k < K; ++k) {
            const float bk = Br[k];
            e.x -= bk * a[k].x;
            e.y -= bk * a[k].y;
            e.z -= bk * a[k].z;
            e.w -= bk * a[k].w;
        }
        acc.x += fabsf(e.x);
        acc.y += fabsf(e.y);
        acc.z += fabsf(e.z);
        acc.w += fabsf(e.w);
    }
    partial4[s * T4 + j4] = acc;
}

// Sum the S partials per float4-column, per-thread argmax over the 4 scalar
// columns, then block argmax via packed (sum_bits<<32 | j) atomicMax.
__global__ __launch_bounds__(256) void reduce_argmax_kernel(
        const float4* __restrict__ partial4, unsigned long long* slot) {
    const int j4 = blockIdx.x * blockDim.x + threadIdx.x;
    unsigned long long key = 0ull;
    if (j4 < T4) {
        float4 sum = make_float4(0.f, 0.f, 0.f, 0.f);
#pragma unroll
        for (int ss = 0; ss < S; ++ss) {
            float4 p = partial4[ss * T4 + j4];
            sum.x += p.x; sum.y += p.y; sum.z += p.z; sum.w += p.w;
        }
        float best = sum.x; int jb = 4 * j4;
        if (sum.y > best) { best = sum.y; jb = 4 * j4 + 1; }
        if (sum.z > best) { best = sum.z; jb = 4 * j4 + 2; }
        if (sum.w > best) { best = sum.w; jb = 4 * j4 + 3; }
        // best >= 0 -> float bit pattern order-preserving as unsigned
        key = (((unsigned long long)__float_as_uint(best)) << 32) | (unsigned int)jb;
    }
#pragma unroll
    for (int off = 32; off > 0; off >>= 1) {
        unsigned long long o = __shfl_down(key, off, 64);
        if (o > key) key = o;
    }
    __shared__ unsigned long long wmax[4];
    const int lane = threadIdx.x & 63, wid = threadIdx.x >> 6;
    if (lane == 0) wmax[wid] = key;
    __syncthreads();
    if (threadIdx.x == 0) {
        unsigned long long bk = wmax[0];
        for (int w = 1; w < 4; ++w)
            if (wmax[w] > bk) bk = wmax[w];
        atomicMax(slot, bk);
    }
}

// Single block, 512 threads, thread i handles row i of P/B.
// Computes residual signs at column j*, B column-L1 argmax k*, gradient,
// optional shrink-chain factor, Adam step, and writes B = shrink(P) in place
// for the next iteration. Resets the argmax slot.
__global__ __launch_bounds__(512) void update_kernel(
        const float* __restrict__ E, const float* __restrict__ A,
        float* __restrict__ B, float* __restrict__ P,
        float* __restrict__ m, float* __restrict__ v,
        unsigned long long* slot, float bias1, float bias2, int shrinkGrad) {
    int i = threadIdx.x;   // 0..511
    __shared__ float colB[K];
    __shared__ int js_s, ks_s;
    if (i < K) colB[i] = 0.f;
    if (i == 0) js_s = (int)((*slot) & 0xffffffffull);
    __syncthreads();
    int js = js_s;

    float b[K];
#pragma unroll
    for (int k = 0; k < K; ++k) b[k] = B[i * K + k];

    // residual sign for row i at column j*
    float r = E[i * T + js];
#pragma unroll
    for (int k = 0; k < K; ++k) r -= b[k] * A[k * T + js];
    float s = sgn(r);

    // B column abs-sums: wave reduce then one LDS atomic per wave per k
#pragma unroll
    for (int k = 0; k < K; ++k) {
        float x = fabsf(b[k]);
#pragma unroll
        for (int off = 32; off > 0; off >>= 1) x += __shfl_down(x, off, 64);
        if ((threadIdx.x & 63) == 0) atomicAdd(&colB[k], x);
    }
    __syncthreads();
    if (i == 0) {
        int kb = 0;
        float best = colB[0];
        for (int k = 1; k < K; ++k)
            if (colB[k] > best) { best = colB[k]; kb = k; }   // first-max tie-break
        ks_s = kb;
        *slot = 0ull;   // reset for next iteration
    }
    __syncthreads();
    int ks = ks_s;

#pragma unroll
    for (int k = 0; k < K; ++k) {
        float g = -s * A[k * T + js];
        if (k == ks) g += LAMBDA1 * sgn(b[k]);
        float p = P[i * K + k];
        if (shrinkGrad) g *= sgn(p) * sgn(p - SHRINK_C);   // d shrink/dp a.e.
        float mm = BETA1 * m[i * K + k] + (1.f - BETA1) * g;
        float vv = BETA2 * v[i * K + k] + (1.f - BETA2) * g * g;
        m[i * K + k] = mm;
        v[i * K + k] = vv;
        p -= LR * (mm / bias1) / (sqrtf(vv / bias2) + ADAM_EPS);
        P[i * K + k] = p;
        B[i * K + k] = sgn(p) * fmaxf(0.f, fabsf(p - SHRINK_C));   // next B = shrink(P)
    }
}

// out = [shrink(P_final) (8192), A (800000)]. B already holds shrink(P_final).
__global__ void output_kernel(const float* __restrict__ B, const float* __restrict__ A,
                              float4* __restrict__ out) {
    int idx = blockIdx.x * blockDim.x + threadIdx.x;   // float4 units
    const int nB4 = (D * K) / 4;                       // 2048
    const int nTot4 = (D * K + K * T) / 4;             // 202048
    if (idx < nB4) {
        out[idx] = ((const float4*)B)[idx];
    } else if (idx < nTot4) {
        out[idx] = ((const float4*)A)[idx - nB4];
    }
}

extern "C" void kernel_launch(void* const* d_in, const int* in_sizes, int n_in,
                              void* d_out, int out_size, void* d_ws, size_t ws_size,
                              hipStream_t stream) {
    const float* E   = (const float*)d_in[0];   // (D, T)
    const float* Bin = (const float*)d_in[1];   // (D, K)
    const float* A   = (const float*)d_in[2];   // (K, T)

    float* P = (float*)d_ws;
    float* m = P + D * K;
    float* v = m + D * K;
    float* B = v + D * K;
    unsigned long long* slot = (unsigned long long*)(B + D * K);   // 16B-aligned
    float4* partial4 = (float4*)(slot + 2);   // S * T4 float4 = 6.4 MB

    init_kernel<<<(D * K + 255) / 256, 256, 0, stream>>>(Bin, P, m, v, B, slot);

    for (int it = 1; it <= 10; ++it) {
        partial_colsum_kernel<<<dim3(CB, S), 256, 0, stream>>>(E, A, B, partial4);
        reduce_argmax_kernel<<<CB, 256, 0, stream>>>(partial4, slot);
        float b1 = 1.f - powf(BETA1, (float)it);
        float b2 = 1.f - powf(BETA2, (float)it);
        update_kernel<<<1, 512, 0, stream>>>(E, A, B, P, m, v, slot, b1, b2,
                                             (it >= 2) ? 1 : 0);
    }

    const int nTot4 = (D * K + K * T) / 4;
    output_kernel<<<(nTot4 + 255) / 256, 256, 0, stream>>>(B, A, (float4*)d_out);
}

// Round 5
// 786.551 us; speedup vs baseline: 2.2642x; 1.0040x over previous
//
#include <hip/hip_runtime.h>

#define D 512
#define T 50000
#define T4 12500          // T/4 float4 columns
#define K 16

#define S 16              // row slices
#define RS (D / S)        // 32 rows per slice
#define CB 49             // column blocks = ceil(T4/256)

#define LAMBDA1 0.3366f
#define LR      0.1f
#define SHRINK_C (LR * LAMBDA1)
#define BETA1   0.9f
#define BETA2   0.999f
#define ADAM_EPS 1e-8f

__device__ __forceinline__ float sgn(float x) {
    return (x > 0.f) ? 1.f : ((x < 0.f) ? -1.f : 0.f);
}

// Initialize P, m, v, B (=P for iter 1), the argmax slot and the block counter.
// d_ws is poisoned 0xAA before every call.
__global__ void init_kernel(const float* __restrict__ Pin, float* __restrict__ P,
                            float* __restrict__ m, float* __restrict__ v,
                            float* __restrict__ B, unsigned long long* slot,
                            unsigned int* cnt) {
    int idx = blockIdx.x * blockDim.x + threadIdx.x;
    if (idx < D * K) {
        float p = Pin[idx];
        P[idx] = p;
        m[idx] = 0.f;
        v[idx] = 0.f;
        B[idx] = p;   // iteration 1 uses the raw parameter
    }
    if (idx == 0) { *slot = 0ull; *cnt = 0u; }
}

// Partial column abs-sums, float4 columns: block (bx, s) covers 1024 scalar
// columns x 32 rows. Explicit 8-deep load pipeline: batch 8 independent
// global_load_dwordx4 before consuming any (latency hiding via ILP).
// Deterministic (no fp atomics), no fences (kernel boundary publishes).
__global__ __launch_bounds__(256) void partial_colsum_kernel(
        const float* __restrict__ E, const float* __restrict__ A,
        const float* __restrict__ B, float4* __restrict__ partial4) {
    const int j4 = blockIdx.x * blockDim.x + threadIdx.x;
    const int s  = blockIdx.y;
    if (j4 >= T4) return;

    const float4* E4 = (const float4*)E;
    const float4* A4 = (const float4*)A;

    float4 a[K];
#pragma unroll
    for (int k = 0; k < K; ++k) a[k] = A4[k * T4 + j4];

    float4 acc = make_float4(0.f, 0.f, 0.f, 0.f);
    const int r0 = s * RS;

    for (int base = 0; base < RS; base += 8) {
        float4 ebuf[8];
#pragma unroll
        for (int u = 0; u < 8; ++u)
            ebuf[u] = E4[(r0 + base + u) * T4 + j4];   // 8 loads in flight
#pragma unroll
        for (int u = 0; u < 8; ++u) {
            const float* Br = B + (r0 + base + u) * K; // wave-uniform -> s_load
            float4 e = ebuf[u];
#pragma unroll
            for (int k = 0; k < K; ++k) {
                const float bk = Br[k];
                e.x -= bk * a[k].x;
                e.y -= bk * a[k].y;
                e.z -= bk * a[k].z;
                e.w -= bk * a[k].w;
            }
            acc.x += fabsf(e.x);
            acc.y += fabsf(e.y);
            acc.z += fabsf(e.z);
            acc.w += fabsf(e.w);
        }
    }
    partial4[s * T4 + j4] = acc;
}

// Fused reduce + argmax + update. 49 blocks sum the S partials per column and
// atomicMax a packed (sum_bits<<32 | j) key into slot. The LAST block (device
// atomic counter; tid0-only threadfence = 49 fences total, cheap) reads the
// winning column and runs the full Adam/shrink update inline, then resets
// slot/cnt for the next iteration.
__global__ __launch_bounds__(256) void reduce_update_kernel(
        const float4* __restrict__ partial4,
        const float* __restrict__ E, const float* __restrict__ A,
        float* __restrict__ B, float* __restrict__ P,
        float* __restrict__ m, float* __restrict__ v,
        unsigned long long* slot, unsigned int* cnt,
        float bias1, float bias2, int shrinkGrad) {
    const int tid = threadIdx.x;
    const int j4 = blockIdx.x * blockDim.x + tid;

    unsigned long long key = 0ull;
    if (j4 < T4) {
        float4 sum = make_float4(0.f, 0.f, 0.f, 0.f);
#pragma unroll
        for (int ss = 0; ss < S; ++ss) {
            float4 p = partial4[ss * T4 + j4];
            sum.x += p.x; sum.y += p.y; sum.z += p.z; sum.w += p.w;
        }
        float best = sum.x; int jb = 4 * j4;
        if (sum.y > best) { best = sum.y; jb = 4 * j4 + 1; }
        if (sum.z > best) { best = sum.z; jb = 4 * j4 + 2; }
        if (sum.w > best) { best = sum.w; jb = 4 * j4 + 3; }
        // best >= 0 -> float bit pattern order-preserving as unsigned
        key = (((unsigned long long)__float_as_uint(best)) << 32) | (unsigned int)jb;
    }
#pragma unroll
    for (int off = 32; off > 0; off >>= 1) {
        unsigned long long o = __shfl_down(key, off, 64);
        if (o > key) key = o;
    }
    __shared__ unsigned long long wmax[4];
    __shared__ int flag_s, js_s, ks_s;
    const int lane = tid & 63, wid = tid >> 6;
    if (lane == 0) wmax[wid] = key;
    __syncthreads();
    if (tid == 0) {
        unsigned long long bk = wmax[0];
        for (int w = 1; w < 4; ++w)
            if (wmax[w] > bk) bk = wmax[w];
        atomicMax(slot, bk);
        __threadfence();   // drain my atomicMax before signaling the counter
        int last = (atomicAdd(cnt, 1u) == CB - 1) ? 1 : 0;
        if (last) {
            __threadfence();   // acquire side
            unsigned long long win = atomicMax(slot, 0ull);  // coherent RMW read
            js_s = (int)(win & 0xffffffffull);
        }
        flag_s = last;
    }
    __syncthreads();
    if (!flag_s) return;

    // ---- last block: parameter update (rows tid and tid+256) ----
    __shared__ float colB[K];
    if (tid < K) colB[tid] = 0.f;
    __syncthreads();
    const int js = js_s;
    const int i0 = tid, i1 = tid + 256;

    float b0[K], b1v[K];
#pragma unroll
    for (int k = 0; k < K; ++k) { b0[k] = B[i0 * K + k]; b1v[k] = B[i1 * K + k]; }

    float r0v = E[i0 * T + js];
    float r1v = E[i1 * T + js];
#pragma unroll
    for (int k = 0; k < K; ++k) {
        const float ak = A[k * T + js];
        r0v -= b0[k] * ak;
        r1v -= b1v[k] * ak;
    }
    const float s0 = sgn(r0v), s1 = sgn(r1v);

    // B column abs-sums: wave reduce then one LDS atomic per wave per k
#pragma unroll
    for (int k = 0; k < K; ++k) {
        float x = fabsf(b0[k]) + fabsf(b1v[k]);
#pragma unroll
        for (int off = 32; off > 0; off >>= 1) x += __shfl_down(x, off, 64);
        if ((tid & 63) == 0) atomicAdd(&colB[k], x);
    }
    __syncthreads();
    if (tid == 0) {
        int kb = 0;
        float best = colB[0];
        for (int k = 1; k < K; ++k)
            if (colB[k] > best) { best = colB[k]; kb = k; }  // first-max tie-break
        ks_s = kb;
    }
    __syncthreads();
    const int ks = ks_s;

#pragma unroll
    for (int k = 0; k < K; ++k) {
        const float ak = A[k * T + js];
#pragma unroll
        for (int h = 0; h < 2; ++h) {
            const int i = h ? i1 : i0;
            const float sg = h ? s1 : s0;
            const float bk = h ? b1v[k] : b0[k];
            float g = -sg * ak;
            if (k == ks) g += LAMBDA1 * sgn(bk);
            float p = P[i * K + k];
            if (shrinkGrad) g *= sgn(p) * sgn(p - SHRINK_C);  // d shrink/dp a.e.
            float mm = BETA1 * m[i * K + k] + (1.f - BETA1) * g;
            float vv = BETA2 * v[i * K + k] + (1.f - BETA2) * g * g;
            m[i * K + k] = mm;
            v[i * K + k] = vv;
            p -= LR * (mm / bias1) / (sqrtf(vv / bias2) + ADAM_EPS);
            P[i * K + k] = p;
            B[i * K + k] = sgn(p) * fmaxf(0.f, fabsf(p - SHRINK_C)); // next B
        }
    }

    // reset for the next iteration; kernel boundary publishes these stores
    if (tid == 0) { *slot = 0ull; *cnt = 0u; }
}

// out = [shrink(P_final) (8192), A (800000)]. B already holds shrink(P_final).
__global__ void output_kernel(const float* __restrict__ B, const float* __restrict__ A,
                              float4* __restrict__ out) {
    int idx = blockIdx.x * blockDim.x + threadIdx.x;   // float4 units
    const int nB4 = (D * K) / 4;                       // 2048
    const int nTot4 = (D * K + K * T) / 4;             // 202048
    if (idx < nB4) {
        out[idx] = ((const float4*)B)[idx];
    } else if (idx < nTot4) {
        out[idx] = ((const float4*)A)[idx - nB4];
    }
}

extern "C" void kernel_launch(void* const* d_in, const int* in_sizes, int n_in,
                              void* d_out, int out_size, void* d_ws, size_t ws_size,
                              hipStream_t stream) {
    const float* E   = (const float*)d_in[0];   // (D, T)
    const float* Bin = (const float*)d_in[1];   // (D, K)
    const float* A   = (const float*)d_in[2];   // (K, T)

    float* P = (float*)d_ws;
    float* m = P + D * K;
    float* v = m + D * K;
    float* B = v + D * K;
    unsigned long long* slot = (unsigned long long*)(B + D * K);   // 16B-aligned
    unsigned int* cnt = (unsigned int*)(slot + 1);
    float4* partial4 = (float4*)(slot + 2);   // S * T4 float4 = 3.2 MB

    init_kernel<<<(D * K + 255) / 256, 256, 0, stream>>>(Bin, P, m, v, B, slot, cnt);

    for (int it = 1; it <= 10; ++it) {
        partial_colsum_kernel<<<dim3(CB, S), 256, 0, stream>>>(E, A, B, partial4);
        float b1 = 1.f - powf(BETA1, (float)it);
        float b2 = 1.f - powf(BETA2, (float)it);
        reduce_update_kernel<<<CB, 256, 0, stream>>>(partial4, E, A, B, P, m, v,
                                                     slot, cnt, b1, b2,
                                                     (it >= 2) ? 1 : 0);
    }

    const int nTot4 = (D * K + K * T) / 4;
    output_kernel<<<(nTot4 + 255) / 256, 256, 0, stream>>>(B, A, (float4*)d_out);
}

// Round 7
// 785.130 us; speedup vs baseline: 2.2683x; 1.0018x over previous
//
#include <hip/hip_runtime.h>

#define D 512
#define T 50000
#define T4 12500          // T/4 float4 columns
#define K 16

#define COLS 16           // float4 columns per block
#define RGS 16            // row groups per block (256 threads = COLS*RGS)
#define RPT (D / RGS)     // 32 rows per thread
#define NBLK ((T4 + COLS - 1) / COLS)   // 782 blocks

#define LAMBDA1 0.3366f
#define LR      0.1f
#define SHRINK_C (LR * LAMBDA1)
#define BETA1   0.9f
#define BETA2   0.999f
#define ADAM_EPS 1e-8f

// native clang vector: __builtin_nontemporal_load accepts this (HIP_vector_type it does not)
typedef float vfloat4 __attribute__((ext_vector_type(4)));

__device__ __forceinline__ float sgn(float x) {
    return (x > 0.f) ? 1.f : ((x < 0.f) ? -1.f : 0.f);
}

// Initialize P, m, v, B (=P for iter 1) and the argmax slot. d_ws is poisoned
// 0xAA before every call, so everything must be re-initialized here.
__global__ void init_kernel(const float* __restrict__ Pin, float* __restrict__ P,
                            float* __restrict__ m, float* __restrict__ v,
                            float* __restrict__ B, unsigned long long* slot) {
    int idx = blockIdx.x * blockDim.x + threadIdx.x;
    if (idx < D * K) {
        float p = Pin[idx];
        P[idx] = p;
        m[idx] = 0.f;
        v[idx] = 0.f;
        B[idx] = p;   // iteration 1 uses the raw parameter
    }
    if (idx == 0) *slot = 0ull;
}

// Full column abs-sum + argmax in ONE kernel. Block = 16 f4-cols x 16
// row-groups; thread (col, rg) accumulates 32 rows of its float4 column,
// LDS-reduces across row-groups, then wave 0 does the block argmax and one
// atomicMax on the packed (sum_bits<<32 | j) slot. B staged to LDS once
// (row index varies per lane -> ds_read broadcast, not L1-thrash VMEM).
// E loads are nontemporal (zero reuse). No partial buffer, A read once.
__global__ __launch_bounds__(256) void colsum_argmax_kernel(
        const float* __restrict__ E, const float* __restrict__ A,
        const float* __restrict__ B, unsigned long long* slot) {
    const int tid = threadIdx.x;
    const int col = tid & (COLS - 1);
    const int rg  = tid >> 4;
    const int j4  = blockIdx.x * COLS + col;
    const bool active = (j4 < T4);

    const vfloat4* E4 = (const vfloat4*)E;
    const vfloat4* A4 = (const vfloat4*)A;
    const vfloat4* B4 = (const vfloat4*)B;

    __shared__ vfloat4 ldsB[D * K / 4];      // 32 KB: full B tile
    __shared__ vfloat4 ldsAcc[RGS][COLS];    // 4 KB: per-(rg,col) partials

#pragma unroll
    for (int u = 0; u < (D * K / 4) / 256; ++u)   // 8 float4 per thread
        ldsB[tid + 256 * u] = B4[tid + 256 * u];
    __syncthreads();

    vfloat4 acc = (vfloat4)(0.f);
    if (active) {
        vfloat4 a[K];
#pragma unroll
        for (int k = 0; k < K; ++k) a[k] = A4[k * T4 + j4];

        const int r0 = rg * RPT;
        for (int base = 0; base < RPT; base += 8) {
            vfloat4 eb[8];
#pragma unroll
            for (int u = 0; u < 8; ++u)
                eb[u] = __builtin_nontemporal_load(&E4[(r0 + base + u) * T4 + j4]);
#pragma unroll
            for (int u = 0; u < 8; ++u) {
                const vfloat4* Br4 = &ldsB[(r0 + base + u) * (K / 4)];
                vfloat4 e = eb[u];
#pragma unroll
                for (int q = 0; q < K / 4; ++q) {
                    const vfloat4 b4 = Br4[q];
                    // same k-order as before: k = 4q+0..3
                    e -= b4.x * a[4*q+0];
                    e -= b4.y * a[4*q+1];
                    e -= b4.z * a[4*q+2];
                    e -= b4.w * a[4*q+3];
                }
                acc.x += fabsf(e.x);
                acc.y += fabsf(e.y);
                acc.z += fabsf(e.z);
                acc.w += fabsf(e.w);
            }
        }
    }
    ldsAcc[rg][col] = acc;
    __syncthreads();

    if (tid < 64) {   // whole wave 0 participates -> shuffles well-defined
        unsigned long long key = 0ull;
        if (tid < COLS) {
            vfloat4 tot = ldsAcc[0][tid];
#pragma unroll
            for (int g = 1; g < RGS; ++g)
                tot += ldsAcc[g][tid];
            const int j4b = blockIdx.x * COLS + tid;
            if (j4b < T4) {
                float best = tot.x; int jb = 4 * j4b;
                if (tot.y > best) { best = tot.y; jb = 4 * j4b + 1; }
                if (tot.z > best) { best = tot.z; jb = 4 * j4b + 2; }
                if (tot.w > best) { best = tot.w; jb = 4 * j4b + 3; }
                // best >= 0 -> float bit pattern order-preserving as unsigned
                key = (((unsigned long long)__float_as_uint(best)) << 32)
                      | (unsigned int)jb;
            }
        }
#pragma unroll
        for (int off = 8; off > 0; off >>= 1) {
            unsigned long long o = __shfl_down(key, off, 64);
            if (o > key) key = o;
        }
        if (tid == 0) atomicMax(slot, key);
    }
}

// Single block, 512 threads, thread i handles row i of P/B.
// Computes residual signs at column j*, B column-L1 argmax k*, gradient,
// optional shrink-chain factor, Adam step, and writes B = shrink(P) in place
// for the next iteration. Resets the argmax slot. (Kernel boundary makes the
// colsum kernel's atomicMax results visible — worked R1-R4.)
__global__ __launch_bounds__(512) void update_kernel(
        const float* __restrict__ E, const float* __restrict__ A,
        float* __restrict__ B, float* __restrict__ P,
        float* __restrict__ m, float* __restrict__ v,
        unsigned long long* slot, float bias1, float bias2, int shrinkGrad) {
    int i = threadIdx.x;   // 0..511
    __shared__ float colB[K];
    __shared__ int js_s, ks_s;
    if (i < K) colB[i] = 0.f;
    if (i == 0) js_s = (int)((*slot) & 0xffffffffull);
    __syncthreads();
    int js = js_s;

    float b[K];
#pragma unroll
    for (int k = 0; k < K; ++k) b[k] = B[i * K + k];

    // residual sign for row i at column j*
    float r = E[i * T + js];
#pragma unroll
    for (int k = 0; k < K; ++k) r -= b[k] * A[k * T + js];
    float s = sgn(r);

    // B column abs-sums: wave reduce then one LDS atomic per wave per k
#pragma unroll
    for (int k = 0; k < K; ++k) {
        float x = fabsf(b[k]);
#pragma unroll
        for (int off = 32; off > 0; off >>= 1) x += __shfl_down(x, off, 64);
        if ((threadIdx.x & 63) == 0) atomicAdd(&colB[k], x);
    }
    __syncthreads();
    if (i == 0) {
        int kb = 0;
        float best = colB[0];
        for (int k = 1; k < K; ++k)
            if (colB[k] > best) { best = colB[k]; kb = k; }   // first-max tie-break
        ks_s = kb;
        *slot = 0ull;   // reset for next iteration
    }
    __syncthreads();
    int ks = ks_s;

#pragma unroll
    for (int k = 0; k < K; ++k) {
        float g = -s * A[k * T + js];
        if (k == ks) g += LAMBDA1 * sgn(b[k]);
        float p = P[i * K + k];
        if (shrinkGrad) g *= sgn(p) * sgn(p - SHRINK_C);   // d shrink/dp a.e.
        float mm = BETA1 * m[i * K + k] + (1.f - BETA1) * g;
        float vv = BETA2 * v[i * K + k] + (1.f - BETA2) * g * g;
        m[i * K + k] = mm;
        v[i * K + k] = vv;
        p -= LR * (mm / bias1) / (sqrtf(vv / bias2) + ADAM_EPS);
        P[i * K + k] = p;
        B[i * K + k] = sgn(p) * fmaxf(0.f, fabsf(p - SHRINK_C));   // next B = shrink(P)
    }
}

// out = [shrink(P_final) (8192), A (800000)]. B already holds shrink(P_final).
__global__ void output_kernel(const float* __restrict__ B, const float* __restrict__ A,
                              float4* __restrict__ out) {
    int idx = blockIdx.x * blockDim.x + threadIdx.x;   // float4 units
    const int nB4 = (D * K) / 4;                       // 2048
    const int nTot4 = (D * K + K * T) / 4;             // 202048
    if (idx < nB4) {
        out[idx] = ((const float4*)B)[idx];
    } else if (idx < nTot4) {
        out[idx] = ((const float4*)A)[idx - nB4];
    }
}

extern "C" void kernel_launch(void* const* d_in, const int* in_sizes, int n_in,
                              void* d_out, int out_size, void* d_ws, size_t ws_size,
                              hipStream_t stream) {
    const float* E   = (const float*)d_in[0];   // (D, T)
    const float* Bin = (const float*)d_in[1];   // (D, K)
    const float* A   = (const float*)d_in[2];   // (K, T)

    float* P = (float*)d_ws;
    float* m = P + D * K;
    float* v = m + D * K;
    float* B = v + D * K;
    unsigned long long* slot = (unsigned long long*)(B + D * K);   // 8B-aligned

    init_kernel<<<(D * K + 255) / 256, 256, 0, stream>>>(Bin, P, m, v, B, slot);

    for (int it = 1; it <= 10; ++it) {
        colsum_argmax_kernel<<<NBLK, 256, 0, stream>>>(E, A, B, slot);
        float b1 = 1.f - powf(BETA1, (float)it);
        float b2 = 1.f - powf(BETA2, (float)it);
        update_kernel<<<1, 512, 0, stream>>>(E, A, B, P, m, v, slot, b1, b2,
                                             (it >= 2) ? 1 : 0);
    }

    const int nTot4 = (D * K + K * T) / 4;
    output_kernel<<<(nTot4 + 255) / 256, 256, 0, stream>>>(B, A, (float4*)d_out);
}